// Round 5
// baseline (825.936 us; speedup 1.0000x reference)
//
#include <hip/hip_runtime.h>

#define OBS   32
#define NC    512
#define CD    16
#define HD    256
#define BATCH 8192
#define EPS   4e-3f

// ---------------------------------------------------------------------------
// Kernel 0: codebook squared norms (fp32 + fp64) and flag-counter zeroing.
// ---------------------------------------------------------------------------
__global__ void cb_norms_kernel(const float* __restrict__ cb,
                                float* __restrict__ n32, double* __restrict__ n64,
                                int* __restrict__ fcnt) {
    if (blockIdx.x == 0 && threadIdx.x == 0) *fcnt = 0;
    int c = blockIdx.x * blockDim.x + threadIdx.x;
    if (c >= NC) return;
    const float* r = cb + c * CD;
    float s32 = 0.f; double s64 = 0.0;
    #pragma unroll
    for (int j = 0; j < CD; ++j) {
        float v = r[j];
        s32 = fmaf(v, v, s32);
        s64 = fma((double)v, (double)v, s64);
    }
    n32[c] = s32; n64[c] = s64;
}

// ---------------------------------------------------------------------------
// Kernel 1: fp32 fused encoder + quantize prefilter. One block = one batch
// row (32 tokens). Wave w owns tokens 8w..8w+7 through phases B-C (no cross-
// wave flow); W1/W2 read straight from global (L2/L3-resident) -> only 5
// barriers per block. h rows padded to 260 (conflict-free); codebook staged
// at stride 18 floats (gcd(18,32)=2 -> 2-way, free). Tokens whose top-2 gap
// < EPS are flagged for the exact fp64 fixup kernel.
// ---------------------------------------------------------------------------
__global__ void __launch_bounds__(256, 4) encoder_kernel(
    const float* __restrict__ obs,
    const float* __restrict__ W0, const float* __restrict__ B0,
    const float* __restrict__ W1, const float* __restrict__ B1,
    const float* __restrict__ W2, const float* __restrict__ B2,
    const float* __restrict__ cb, const float* __restrict__ n32,
    int* __restrict__ idxbuf, int* __restrict__ fcnt, int* __restrict__ flist)
{
    // smem: phases A-C = hbuf[32][260] (8320 floats); phase D = cbs[512][18]
    // (9216 floats). embs/xrow separate.
    __shared__ float smem[9216];        // 36864 B
    __shared__ float embs[OBS * CD];    //  2048 B
    __shared__ float xrow[OBS];         //   128 B  (total 39040 B -> 4 blk/CU)

    const int tid = threadIdx.x;
    const int blk = blockIdx.x;

    if (tid < OBS) xrow[tid] = obs[blk * OBS + tid];
    __syncthreads();

    // ---- phase A: h0[t][j] = relu(x_t*W0[0,j] + W0[1+t,j] + b0[j]) ----
    {
        const int j = tid;
        const float w0j = W0[j];
        const float b0j = B0[j];
        for (int t = 0; t < OBS; ++t) {
            float pre = fmaf(xrow[t], w0j, W0[(1 + t) * HD + j]) + b0j;
            smem[t * 260 + j] = fmaxf(pre, 0.f);
        }
    }
    __syncthreads();

    // ---- phase B: h1 = relu(h0 @ W1 + b1); 8 tokens x 4 cols per thread,
    //      W1 from global, zero barriers in the k-loop ----
    const int c0 = (tid & 63) * 4;      // 64 col groups x 4 cols = 256
    const int t0 = (tid >> 6) * 8;      // wave-uniform token group

    float acc[8][4];
    #pragma unroll
    for (int tt = 0; tt < 8; ++tt)
        #pragma unroll
        for (int u = 0; u < 4; ++u) acc[tt][u] = 0.f;

    for (int k = 0; k < 256; k += 4) {
        float4 w0 = *(const float4*)(W1 + (k + 0) * HD + c0);
        float4 w1 = *(const float4*)(W1 + (k + 1) * HD + c0);
        float4 w2 = *(const float4*)(W1 + (k + 2) * HD + c0);
        float4 w3 = *(const float4*)(W1 + (k + 3) * HD + c0);
        float4 hv[8];
        #pragma unroll
        for (int tt = 0; tt < 8; ++tt)       // wave-uniform addr: broadcast
            hv[tt] = *(const float4*)&smem[(t0 + tt) * 260 + k];
        #pragma unroll
        for (int tt = 0; tt < 8; ++tt) {
            float4 h = hv[tt];
            acc[tt][0] = fmaf(h.x, w0.x, acc[tt][0]);
            acc[tt][1] = fmaf(h.x, w0.y, acc[tt][1]);
            acc[tt][2] = fmaf(h.x, w0.z, acc[tt][2]);
            acc[tt][3] = fmaf(h.x, w0.w, acc[tt][3]);
            acc[tt][0] = fmaf(h.y, w1.x, acc[tt][0]);
            acc[tt][1] = fmaf(h.y, w1.y, acc[tt][1]);
            acc[tt][2] = fmaf(h.y, w1.z, acc[tt][2]);
            acc[tt][3] = fmaf(h.y, w1.w, acc[tt][3]);
            acc[tt][0] = fmaf(h.z, w2.x, acc[tt][0]);
            acc[tt][1] = fmaf(h.z, w2.y, acc[tt][1]);
            acc[tt][2] = fmaf(h.z, w2.z, acc[tt][2]);
            acc[tt][3] = fmaf(h.z, w2.w, acc[tt][3]);
            acc[tt][0] = fmaf(h.w, w3.x, acc[tt][0]);
            acc[tt][1] = fmaf(h.w, w3.y, acc[tt][1]);
            acc[tt][2] = fmaf(h.w, w3.z, acc[tt][2]);
            acc[tt][3] = fmaf(h.w, w3.w, acc[tt][3]);
        }
    }

    {   // h1 = relu(acc + b1) -> hbuf (same wave re-reads these rows in C)
        float4 b1v = *(const float4*)(B1 + c0);
        #pragma unroll
        for (int tt = 0; tt < 8; ++tt) {
            float4 o;
            o.x = fmaxf(acc[tt][0] + b1v.x, 0.f);
            o.y = fmaxf(acc[tt][1] + b1v.y, 0.f);
            o.z = fmaxf(acc[tt][2] + b1v.z, 0.f);
            o.w = fmaxf(acc[tt][3] + b1v.w, 0.f);
            *(float4*)&smem[(t0 + tt) * 260 + c0] = o;
        }
    }
    __syncthreads();   // cross-lane h1 visibility (cheap insurance)

    // ---- phase C: emb = h1 @ W2 + b2; thread = (token, dim-pair), W2 global ----
    {
        const int t  = tid >> 3;
        const int dp = (tid & 7) * 2;    // dims dp, dp+1
        float a0 = 0.f, a1 = 0.f, b0 = 0.f, b1 = 0.f;
        for (int k = 0; k < HD; k += 4) {
            float4 h = *(const float4*)&smem[t * 260 + k];
            float2 wa = *(const float2*)(W2 + (k + 0) * CD + dp);
            float2 wb = *(const float2*)(W2 + (k + 1) * CD + dp);
            float2 wc = *(const float2*)(W2 + (k + 2) * CD + dp);
            float2 wd = *(const float2*)(W2 + (k + 3) * CD + dp);
            a0 = fmaf(h.x, wa.x, a0); a1 = fmaf(h.x, wa.y, a1);
            b0 = fmaf(h.y, wb.x, b0); b1 = fmaf(h.y, wb.y, b1);
            a0 = fmaf(h.z, wc.x, a0); a1 = fmaf(h.z, wc.y, a1);
            b0 = fmaf(h.w, wd.x, b0); b1 = fmaf(h.w, wd.y, b1);
        }
        float e0 = (a0 + b0) + B2[dp];
        float e1 = (a1 + b1) + B2[dp + 1];
        *(float2*)&embs[t * CD + dp] = make_float2(e0, e1);
    }
    __syncthreads();                    // embs done; hbuf reads done

    // stage codebook into smem overlay, stride 18 floats (2-way = free)
    for (int r = tid; r < NC; r += 256) {
        const float2* src = (const float2*)(cb + r * CD);
        float* dst = &smem[r * 18];
        #pragma unroll
        for (int i = 0; i < 8; ++i) *(float2*)&dst[2 * i] = src[i];
    }
    __syncthreads();

    // ---- phase D: exact fp32 top-2 over 512 codes; flag near-ties ----
    {
        const int s  = tid & 31;        // 32 lanes/token-group, 16 codes each
        const int tD = (tid >> 5) * 4;  // 4 tokens per thread
        float e[4][CD];
        #pragma unroll
        for (int j = 0; j < 4; ++j)
            #pragma unroll
            for (int q4 = 0; q4 < 4; ++q4) {
                float4 v = *(const float4*)&embs[(tD + j) * CD + q4 * 4];
                e[j][q4 * 4 + 0] = v.x; e[j][q4 * 4 + 1] = v.y;
                e[j][q4 * 4 + 2] = v.z; e[j][q4 * 4 + 3] = v.w;
            }
        float d1[4], d2[4]; int i1[4], i2[4];
        #pragma unroll
        for (int j = 0; j < 4; ++j) { d1[j] = d2[j] = 3.4e38f; i1[j] = i2[j] = 0x7fffffff; }

        for (int cc = 0; cc < 16; ++cc) {
            const int ci = cc * 32 + s;
            const float* cr = &smem[ci * 18];
            float c_[CD];
            #pragma unroll
            for (int i = 0; i < 8; ++i) {
                float2 p = *(const float2*)&cr[2 * i];
                c_[2 * i] = p.x; c_[2 * i + 1] = p.y;
            }
            float cn = n32[ci];
            #pragma unroll
            for (int j = 0; j < 4; ++j) {
                float dA = 0.f, dB = 0.f;
                #pragma unroll
                for (int q = 0; q < 8; ++q) {
                    dA = fmaf(c_[2 * q],     e[j][2 * q],     dA);
                    dB = fmaf(c_[2 * q + 1], e[j][2 * q + 1], dB);
                }
                float d = fmaf(-2.f, dA + dB, cn);
                if (d < d1[j])      { d2[j] = d1[j]; i2[j] = i1[j]; d1[j] = d; i1[j] = ci; }
                else if (d < d2[j]) { d2[j] = d;  i2[j] = ci; }
            }
        }
        // width-32 top-2 merge reduce (tie -> low index)
        #pragma unroll
        for (int off = 16; off >= 1; off >>= 1) {
            #pragma unroll
            for (int j = 0; j < 4; ++j) {
                float od1 = __shfl_down(d1[j], off, 32);
                int   oi1 = __shfl_down(i1[j], off, 32);
                float od2 = __shfl_down(d2[j], off, 32);
                int   oi2 = __shfl_down(i2[j], off, 32);
                bool ob = (od1 < d1[j]) || (od1 == d1[j] && oi1 < i1[j]);
                float n1d, n2d; int n1i, n2i;
                if (ob) {
                    n1d = od1; n1i = oi1;
                    bool t2 = (d1[j] < od2) || (d1[j] == od2 && i1[j] < oi2);
                    n2d = t2 ? d1[j] : od2; n2i = t2 ? i1[j] : oi2;
                } else {
                    n1d = d1[j]; n1i = i1[j];
                    bool t2 = (od1 < d2[j]) || (od1 == d2[j] && oi1 < i2[j]);
                    n2d = t2 ? od1 : d2[j]; n2i = t2 ? oi1 : i2[j];
                }
                d1[j] = n1d; i1[j] = n1i; d2[j] = n2d; i2[j] = n2i;
            }
        }
        if (s == 0) {
            int nf = 0, ft[4];
            #pragma unroll
            for (int j = 0; j < 4; ++j) {
                int T = blk * OBS + tD + j;
                idxbuf[T] = i1[j];
                if (d2[j] - d1[j] < EPS) ft[nf++] = T;
            }
            if (nf) {
                int base = atomicAdd(fcnt, nf);
                for (int k = 0; k < nf; ++k) flist[base + k] = ft[k];
            }
        }
    }
}

// ---------------------------------------------------------------------------
// Kernel 2: fp64 exact re-solve for flagged (near-tie) tokens. One block per
// flagged token, grid-stride. Overwrites idxbuf[T] with the fp64 argmin.
// ---------------------------------------------------------------------------
__global__ void __launch_bounds__(256) fixup_kernel(
    const float* __restrict__ obs,
    const float* __restrict__ W0, const float* __restrict__ B0,
    const float* __restrict__ W1, const float* __restrict__ B1,
    const float* __restrict__ W2, const float* __restrict__ B2,
    const float* __restrict__ cb, const double* __restrict__ n64,
    const int* __restrict__ fcnt, const int* __restrict__ flist,
    int* __restrict__ idxbuf)
{
    __shared__ double h0s[HD];
    __shared__ double h1s[HD];
    __shared__ double ep[16][17];
    __shared__ double es[CD];
    __shared__ double dmin[256];
    __shared__ int    imin[256];

    int n = *fcnt;
    if (n > BATCH * OBS) n = BATCH * OBS;
    const int j = threadIdx.x;

    for (int f = blockIdx.x; f < n; f += gridDim.x) {
        const int T = flist[f];
        const int b = T >> 5, t = T & 31;
        const double x = (double)obs[b * OBS + t];
        {
            double a = fma(x, (double)W0[j], (double)W0[(1 + t) * HD + j])
                     + (double)B0[j];
            h0s[j] = a > 0.0 ? a : 0.0;
        }
        __syncthreads();
        {
            double s = 0.0;
            for (int k = 0; k < HD; ++k)
                s = fma(h0s[k], (double)W1[k * HD + j], s);
            s += (double)B1[j];
            h1s[j] = s > 0.0 ? s : 0.0;
        }
        __syncthreads();
        {
            const int d = j & 15, part = j >> 4;
            double s = 0.0;
            for (int k = part * 16; k < part * 16 + 16; ++k)
                s = fma(h1s[k], (double)W2[k * CD + d], s);
            ep[part][d] = s;
        }
        __syncthreads();
        if (j < CD) {
            double s = 0.0;
            for (int p = 0; p < 16; ++p) s += ep[p][j];
            es[j] = s + (double)B2[j];
        }
        __syncthreads();
        {
            double best = 1e300; int bi = 0x7fffffff;
            for (int c = j; c < NC; c += 256) {
                double dot = 0.0;
                #pragma unroll
                for (int q = 0; q < CD; ++q)
                    dot = fma(es[q], (double)cb[c * CD + q], dot);
                double D = n64[c] - 2.0 * dot;
                if (D < best || (D == best && c < bi)) { best = D; bi = c; }
            }
            dmin[j] = best; imin[j] = bi;
        }
        __syncthreads();
        if (j == 0) {
            double best = dmin[0]; int bi = imin[0];
            for (int k = 1; k < 256; ++k)
                if (dmin[k] < best || (dmin[k] == best && imin[k] < bi)) {
                    best = dmin[k]; bi = imin[k];
                }
            idxbuf[T] = bi;
        }
        __syncthreads();
    }
}

// ---------------------------------------------------------------------------
// Kernel 3: decoder MLP 512 -> 256 -> 256 -> 32, 16 batch rows per block.
// Gathers q rows from the codebook via idxbuf (q never materialized).
// ---------------------------------------------------------------------------
__global__ void __launch_bounds__(256) decoder_kernel(
    const int* __restrict__ idx, const float* __restrict__ cbk,
    const float* __restrict__ W0, const float* __restrict__ B0,
    const float* __restrict__ W1, const float* __restrict__ B1,
    const float* __restrict__ W2, const float* __restrict__ B2,
    float* __restrict__ out)
{
    __shared__ float qb[16][512];   // 32 KB: q, later reused as h2[16][256]
    __shared__ float hb[16][256];   // 16 KB
    const int tid = threadIdx.x;
    const int row0 = blockIdx.x * 16;

    {   // gather q rows: 2 tokens per thread from L1-resident codebook
        const int base = row0 * OBS;
        #pragma unroll
        for (int m = 0; m < 2; ++m) {
            int g = tid * 2 + m;
            int ciq = idx[base + g];
            const float4* src = (const float4*)(cbk + ciq * CD);
            float4* dst = (float4*)&qb[g >> 5][(g & 31) * CD];
            dst[0] = src[0]; dst[1] = src[1]; dst[2] = src[2]; dst[3] = src[3];
        }
    }
    __syncthreads();

    const int jg = tid & 63, tg = tid >> 6;
    const int j0 = jg * 4, r0 = tg * 4;

    // ---- layer 0: K=512 ----
    {
        float acA[4][4], acB[4][4];
        #pragma unroll
        for (int tt = 0; tt < 4; ++tt)
            #pragma unroll
            for (int u = 0; u < 4; ++u) { acA[tt][u] = 0.f; acB[tt][u] = 0.f; }
        for (int k = 0; k < 512; k += 4) {
            float hr[4][4];
            #pragma unroll
            for (int tt = 0; tt < 4; ++tt) {
                float4 hv = *(const float4*)&qb[r0 + tt][k];
                hr[tt][0] = hv.x; hr[tt][1] = hv.y; hr[tt][2] = hv.z; hr[tt][3] = hv.w;
            }
            #pragma unroll
            for (int p = 0; p < 4; ++p) {
                float4 w = *(const float4*)(W0 + (k + p) * 256 + j0);
                if (p < 2) {
                    #pragma unroll
                    for (int tt = 0; tt < 4; ++tt) {
                        acA[tt][0] = fmaf(hr[tt][p], w.x, acA[tt][0]);
                        acA[tt][1] = fmaf(hr[tt][p], w.y, acA[tt][1]);
                        acA[tt][2] = fmaf(hr[tt][p], w.z, acA[tt][2]);
                        acA[tt][3] = fmaf(hr[tt][p], w.w, acA[tt][3]);
                    }
                } else {
                    #pragma unroll
                    for (int tt = 0; tt < 4; ++tt) {
                        acB[tt][0] = fmaf(hr[tt][p], w.x, acB[tt][0]);
                        acB[tt][1] = fmaf(hr[tt][p], w.y, acB[tt][1]);
                        acB[tt][2] = fmaf(hr[tt][p], w.z, acB[tt][2]);
                        acB[tt][3] = fmaf(hr[tt][p], w.w, acB[tt][3]);
                    }
                }
            }
        }
        #pragma unroll
        for (int tt = 0; tt < 4; ++tt)
            #pragma unroll
            for (int u = 0; u < 4; ++u)
                hb[r0 + tt][j0 + u] = fmaxf((acA[tt][u] + acB[tt][u]) + B0[j0 + u], 0.f);
    }
    __syncthreads();

    // ---- layer 1: K=256, write h2 into qb storage ----
    float* h2 = &qb[0][0];
    {
        float acA[4][4], acB[4][4];
        #pragma unroll
        for (int tt = 0; tt < 4; ++tt)
            #pragma unroll
            for (int u = 0; u < 4; ++u) { acA[tt][u] = 0.f; acB[tt][u] = 0.f; }
        for (int k = 0; k < 256; k += 4) {
            float hr[4][4];
            #pragma unroll
            for (int tt = 0; tt < 4; ++tt) {
                float4 hv = *(const float4*)&hb[r0 + tt][k];
                hr[tt][0] = hv.x; hr[tt][1] = hv.y; hr[tt][2] = hv.z; hr[tt][3] = hv.w;
            }
            #pragma unroll
            for (int p = 0; p < 4; ++p) {
                float4 w = *(const float4*)(W1 + (k + p) * 256 + j0);
                if (p < 2) {
                    #pragma unroll
                    for (int tt = 0; tt < 4; ++tt) {
                        acA[tt][0] = fmaf(hr[tt][p], w.x, acA[tt][0]);
                        acA[tt][1] = fmaf(hr[tt][p], w.y, acA[tt][1]);
                        acA[tt][2] = fmaf(hr[tt][p], w.z, acA[tt][2]);
                        acA[tt][3] = fmaf(hr[tt][p], w.w, acA[tt][3]);
                    }
                } else {
                    #pragma unroll
                    for (int tt = 0; tt < 4; ++tt) {
                        acB[tt][0] = fmaf(hr[tt][p], w.x, acB[tt][0]);
                        acB[tt][1] = fmaf(hr[tt][p], w.y, acB[tt][1]);
                        acB[tt][2] = fmaf(hr[tt][p], w.z, acB[tt][2]);
                        acB[tt][3] = fmaf(hr[tt][p], w.w, acB[tt][3]);
                    }
                }
            }
        }
        __syncthreads();
        #pragma unroll
        for (int tt = 0; tt < 4; ++tt)
            #pragma unroll
            for (int u = 0; u < 4; ++u)
                h2[(r0 + tt) * 256 + j0 + u] =
                    fmaxf((acA[tt][u] + acB[tt][u]) + B1[j0 + u], 0.f);
    }
    __syncthreads();

    // ---- layer 2: N=32 output, no relu ----
    {
        const int c  = tid & 31;
        const int rg = tid >> 5;
        for (int rr = rg; rr < 16; rr += 8) {
            float a0 = 0.f, a1 = 0.f, a2 = 0.f, a3 = 0.f;
            #pragma unroll 4
            for (int k = 0; k < 256; k += 4) {
                float4 hv = *(const float4*)&h2[rr * 256 + k];
                a0 = fmaf(hv.x, W2[(k + 0) * 32 + c], a0);
                a1 = fmaf(hv.y, W2[(k + 1) * 32 + c], a1);
                a2 = fmaf(hv.z, W2[(k + 2) * 32 + c], a2);
                a3 = fmaf(hv.w, W2[(k + 3) * 32 + c], a3);
            }
            out[(row0 + rr) * 32 + c] = ((a0 + a1) + (a2 + a3)) + B2[c];
        }
    }
}

// ---------------------------------------------------------------------------
extern "C" void kernel_launch(void* const* d_in, const int* in_sizes, int n_in,
                              void* d_out, int out_size, void* d_ws, size_t ws_size,
                              hipStream_t stream) {
    (void)in_sizes; (void)n_in; (void)out_size; (void)ws_size;
    const float* obs = (const float*)d_in[0];
    const float* eW0 = (const float*)d_in[1];
    const float* eb0 = (const float*)d_in[2];
    const float* eW1 = (const float*)d_in[3];
    const float* eb1 = (const float*)d_in[4];
    const float* eW2 = (const float*)d_in[5];
    const float* eb2 = (const float*)d_in[6];
    const float* dW0 = (const float*)d_in[7];
    const float* db0 = (const float*)d_in[8];
    const float* dW1 = (const float*)d_in[9];
    const float* db1 = (const float*)d_in[10];
    const float* dW2 = (const float*)d_in[11];
    const float* db2 = (const float*)d_in[12];
    const float* cb  = (const float*)d_in[13];

    char*   ws    = (char*)d_ws;
    float*  n32   = (float*)ws;                          // 2 KB
    double* n64   = (double*)(ws + 4096);                // 4 KB
    int*    fcnt  = (int*)(ws + 8192);                   // 4 B
    int*    flist = (int*)(ws + 8448);                   // 1 MB (worst case)
    int*    idxb  = (int*)(ws + 8448 + 1048576);         // 1 MB

    cb_norms_kernel<<<2, 256, 0, stream>>>(cb, n32, n64, fcnt);
    encoder_kernel<<<BATCH, 256, 0, stream>>>(obs, eW0, eb0, eW1, eb1, eW2, eb2,
                                              cb, n32, idxb, fcnt, flist);
    fixup_kernel<<<256, 256, 0, stream>>>(obs, eW0, eb0, eW1, eb1, eW2, eb2,
                                          cb, n64, fcnt, flist, idxb);
    decoder_kernel<<<BATCH / 16, 256, 0, stream>>>(idxb, cb, dW0, db0, dW1, db1,
                                                   dW2, db2, (float*)d_out);
}

// Round 6
// 796.235 us; speedup vs baseline: 1.0373x; 1.0373x over previous
//
#include <hip/hip_runtime.h>

#define OBS   32
#define NC    512
#define CD    16
#define HD    256
#define BATCH 8192
#define EPS   4e-3f

// ---------------------------------------------------------------------------
// Kernel 0: codebook squared norms (fp32 + fp64) and flag-counter zeroing.
// ---------------------------------------------------------------------------
__global__ void cb_norms_kernel(const float* __restrict__ cb,
                                float* __restrict__ n32, double* __restrict__ n64,
                                int* __restrict__ fcnt) {
    if (blockIdx.x == 0 && threadIdx.x == 0) *fcnt = 0;
    int c = blockIdx.x * blockDim.x + threadIdx.x;
    if (c >= NC) return;
    const float* r = cb + c * CD;
    float s32 = 0.f; double s64 = 0.0;
    #pragma unroll
    for (int j = 0; j < CD; ++j) {
        float v = r[j];
        s32 = fmaf(v, v, s32);
        s64 = fma((double)v, (double)v, s64);
    }
    n32[c] = s32; n64[c] = s64;
}

// ---------------------------------------------------------------------------
// Kernel 1: fp32 fused encoder + quantize prefilter. One block = one batch
// row (32 tokens). W1 staged in LDS in 16-row chunks with REGISTER PREFETCH
// (global->reg load of chunk kc+1 overlaps FMA on chunk kc; barriers carry
// only LDS drains). All LDS access patterns broadcast / 2-way (free).
// Tokens whose fp32 top-2 gap < EPS go to the exact fp64 fixup kernel.
// ---------------------------------------------------------------------------
__global__ void __launch_bounds__(256, 3) encoder_kernel(
    const float* __restrict__ obs,
    const float* __restrict__ W0, const float* __restrict__ B0,
    const float* __restrict__ W1, const float* __restrict__ B1,
    const float* __restrict__ W2, const float* __restrict__ B2,
    const float* __restrict__ cb, const float* __restrict__ n32,
    int* __restrict__ idxbuf, int* __restrict__ fcnt, int* __restrict__ flist)
{
    // smem: hbuf[32][256] (8192 f) + wchunk[16][260] (4160 f) = 12352 floats.
    // Phase D overlays smem as cbs[512][18] (9216 f; slot16 = |c|^2).
    __shared__ float smem[12352];       // 49408 B
    __shared__ float embs[OBS * CD];    //  2048 B
    __shared__ float xrow[OBS];         //   128 B  (51584 B -> 3 blk/CU)
    float* const hbuf   = smem;
    float* const wchunk = smem + 8192;

    const int tid = threadIdx.x;
    const int blk = blockIdx.x;

    if (tid < OBS) xrow[tid] = obs[blk * OBS + tid];

    // W1 staging slice: row pr (within chunk), 64B run at col pc
    const int pr = tid & 15;
    const int pc = (tid >> 4) * 16;
    float4 pf0, pf1, pf2, pf3;
    {   // prefetch chunk 0 (lands during phase A)
        const float4* p = (const float4*)(W1 + pr * HD + pc);
        pf0 = p[0]; pf1 = p[1]; pf2 = p[2]; pf3 = p[3];
    }
    __syncthreads();                    // xrow visible

    // ---- phase A: h0[t][j] = relu(x_t*W0[0,j] + W0[1+t,j] + b0[j]) ----
    {
        const int j = tid;
        const float w0j = W0[j];
        const float b0j = B0[j];
        for (int t = 0; t < OBS; ++t) {
            float pre = fmaf(xrow[t], w0j, W0[(1 + t) * HD + j]) + b0j;
            hbuf[t * 256 + j] = fmaxf(pre, 0.f);
        }
    }

    // ---- phase B: h1 = relu(h0 @ W1 + b1); 8 tokens x 4 cols / thread ----
    const int c0 = (tid & 63) * 4;      // 64 col groups x 4 cols
    const int t0 = (tid >> 6) * 8;      // wave-uniform token group

    float acc[8][4];
    #pragma unroll
    for (int tt = 0; tt < 8; ++tt)
        #pragma unroll
        for (int u = 0; u < 4; ++u) acc[tt][u] = 0.f;

    for (int kc = 0; kc < 16; ++kc) {
        __syncthreads();                // prev chunk reads done (kc=0: phase A)
        {   // write prefetched chunk; offsets 4*pr mod 32 -> 2-way, free
            float4* dst = (float4*)&wchunk[pr * 260 + pc];
            dst[0] = pf0; dst[1] = pf1; dst[2] = pf2; dst[3] = pf3;
        }
        __syncthreads();                // chunk visible
        if (kc < 15) {                  // prefetch next chunk during FMA
            const float4* p = (const float4*)(W1 + ((kc + 1) * 16 + pr) * HD + pc);
            pf0 = p[0]; pf1 = p[1]; pf2 = p[2]; pf3 = p[3];
        }
        const int kb = kc * 16;
        #pragma unroll
        for (int kk = 0; kk < 16; kk += 4) {
            float4 hv[8];
            #pragma unroll
            for (int tt = 0; tt < 8; ++tt)      // wave-uniform: broadcast
                hv[tt] = *(const float4*)&hbuf[(t0 + tt) * 256 + kb + kk];
            #pragma unroll
            for (int q = 0; q < 4; ++q) {
                float4 w = *(const float4*)&wchunk[(kk + q) * 260 + c0];
                #pragma unroll
                for (int tt = 0; tt < 8; ++tt) {
                    float h = (q == 0) ? hv[tt].x : (q == 1) ? hv[tt].y
                             : (q == 2) ? hv[tt].z : hv[tt].w;
                    acc[tt][0] = fmaf(h, w.x, acc[tt][0]);
                    acc[tt][1] = fmaf(h, w.y, acc[tt][1]);
                    acc[tt][2] = fmaf(h, w.z, acc[tt][2]);
                    acc[tt][3] = fmaf(h, w.w, acc[tt][3]);
                }
            }
        }
    }

    {   // h1 = relu(acc + b1) -> hbuf
        float4 b1v = *(const float4*)(B1 + c0);
        #pragma unroll
        for (int tt = 0; tt < 8; ++tt) {
            float4 o;
            o.x = fmaxf(acc[tt][0] + b1v.x, 0.f);
            o.y = fmaxf(acc[tt][1] + b1v.y, 0.f);
            o.z = fmaxf(acc[tt][2] + b1v.z, 0.f);
            o.w = fmaxf(acc[tt][3] + b1v.w, 0.f);
            *(float4*)&hbuf[(t0 + tt) * 256 + c0] = o;
        }
    }
    __syncthreads();                    // last W1 chunk reads done; h1 visible

    {   // stage W2^T into wchunk: W2t[d][k], stride 260 (writes free)
        const int d = tid & 15, kb = (tid >> 4) * 16;
        float tmp[16];
        #pragma unroll
        for (int i = 0; i < 16; ++i) tmp[i] = W2[(kb + i) * CD + d];
        float4* dst = (float4*)&wchunk[d * 260 + kb];
        #pragma unroll
        for (int i = 0; i < 4; ++i)
            dst[i] = make_float4(tmp[4*i], tmp[4*i+1], tmp[4*i+2], tmp[4*i+3]);
    }
    __syncthreads();

    // ---- phase C: emb = h1 @ W2 + b2; thread = (token, dims {dp, dp+8}) ----
    {
        const int t  = tid >> 3;
        const int dp = tid & 7;
        float a0 = 0.f, a1 = 0.f;
        #pragma unroll 4
        for (int k = 0; k < HD; k += 4) {
            float4 h  = *(const float4*)&hbuf[t * 256 + k];
            float4 wA = *(const float4*)&wchunk[dp * 260 + k];
            float4 wB = *(const float4*)&wchunk[(dp + 8) * 260 + k];
            a0 = fmaf(h.x, wA.x, a0); a1 = fmaf(h.x, wB.x, a1);
            a0 = fmaf(h.y, wA.y, a0); a1 = fmaf(h.y, wB.y, a1);
            a0 = fmaf(h.z, wA.z, a0); a1 = fmaf(h.z, wB.z, a1);
            a0 = fmaf(h.w, wA.w, a0); a1 = fmaf(h.w, wB.w, a1);
        }
        embs[t * CD + dp]     = a0 + B2[dp];
        embs[t * CD + dp + 8] = a1 + B2[dp + 8];
    }
    __syncthreads();                    // embs done; hbuf/wchunk reads done

    // stage codebook + norm into overlay, stride 18 (writes conflict-free)
    for (int r = tid; r < NC; r += 256) {
        const float2* src = (const float2*)(cb + r * CD);
        float* dst = &smem[r * 18];
        #pragma unroll
        for (int i = 0; i < 8; ++i) *(float2*)&dst[2 * i] = src[i];
        dst[16] = n32[r];
    }
    __syncthreads();

    // ---- phase D: exact fp32 top-2 over 512 codes; flag near-ties ----
    {
        const int s  = tid & 31;        // 32 lanes/token-group, 16 codes each
        const int tD = (tid >> 5) * 4;  // 4 tokens per thread
        float e[4][CD];
        #pragma unroll
        for (int j = 0; j < 4; ++j)
            #pragma unroll
            for (int q4 = 0; q4 < 4; ++q4) {
                float4 v = *(const float4*)&embs[(tD + j) * CD + q4 * 4];
                e[j][q4 * 4 + 0] = v.x; e[j][q4 * 4 + 1] = v.y;
                e[j][q4 * 4 + 2] = v.z; e[j][q4 * 4 + 3] = v.w;
            }
        float d1[4], d2[4]; int i1[4], i2[4];
        #pragma unroll
        for (int j = 0; j < 4; ++j) { d1[j] = d2[j] = 3.4e38f; i1[j] = i2[j] = 0x7fffffff; }

        for (int cc = 0; cc < 16; ++cc) {
            const int ci = cc * 32 + s;
            const float* cr = &smem[ci * 18];
            float c_[CD];
            #pragma unroll
            for (int i = 0; i < 8; ++i) {
                float2 p = *(const float2*)&cr[2 * i];
                c_[2 * i] = p.x; c_[2 * i + 1] = p.y;
            }
            float cn = cr[16];
            #pragma unroll
            for (int j = 0; j < 4; ++j) {
                float dA = 0.f, dB = 0.f;
                #pragma unroll
                for (int q = 0; q < 8; ++q) {
                    dA = fmaf(c_[2 * q],     e[j][2 * q],     dA);
                    dB = fmaf(c_[2 * q + 1], e[j][2 * q + 1], dB);
                }
                float d = fmaf(-2.f, dA + dB, cn);
                if (d < d1[j])      { d2[j] = d1[j]; i2[j] = i1[j]; d1[j] = d; i1[j] = ci; }
                else if (d < d2[j]) { d2[j] = d;  i2[j] = ci; }
            }
        }
        // width-32 top-2 merge reduce (tie -> low index)
        #pragma unroll
        for (int off = 16; off >= 1; off >>= 1) {
            #pragma unroll
            for (int j = 0; j < 4; ++j) {
                float od1 = __shfl_down(d1[j], off, 32);
                int   oi1 = __shfl_down(i1[j], off, 32);
                float od2 = __shfl_down(d2[j], off, 32);
                int   oi2 = __shfl_down(i2[j], off, 32);
                bool ob = (od1 < d1[j]) || (od1 == d1[j] && oi1 < i1[j]);
                float n1d, n2d; int n1i, n2i;
                if (ob) {
                    n1d = od1; n1i = oi1;
                    bool t2 = (d1[j] < od2) || (d1[j] == od2 && i1[j] < oi2);
                    n2d = t2 ? d1[j] : od2; n2i = t2 ? i1[j] : oi2;
                } else {
                    n1d = d1[j]; n1i = i1[j];
                    bool t2 = (od1 < d2[j]) || (od1 == d2[j] && oi1 < i2[j]);
                    n2d = t2 ? od1 : d2[j]; n2i = t2 ? oi1 : i2[j];
                }
                d1[j] = n1d; i1[j] = n1i; d2[j] = n2d; i2[j] = n2i;
            }
        }
        if (s == 0) {
            int nf = 0, ft[4];
            #pragma unroll
            for (int j = 0; j < 4; ++j) {
                int T = blk * OBS + tD + j;
                idxbuf[T] = i1[j];
                if (d2[j] - d1[j] < EPS) ft[nf++] = T;
            }
            if (nf) {
                int base = atomicAdd(fcnt, nf);
                for (int k = 0; k < nf; ++k) flist[base + k] = ft[k];
            }
        }
    }
}

// ---------------------------------------------------------------------------
// Kernel 2: fp64 exact re-solve for flagged (near-tie) tokens. One block per
// flagged token, grid-stride. Overwrites idxbuf[T] with the fp64 argmin.
// ---------------------------------------------------------------------------
__global__ void __launch_bounds__(256) fixup_kernel(
    const float* __restrict__ obs,
    const float* __restrict__ W0, const float* __restrict__ B0,
    const float* __restrict__ W1, const float* __restrict__ B1,
    const float* __restrict__ W2, const float* __restrict__ B2,
    const float* __restrict__ cb, const double* __restrict__ n64,
    const int* __restrict__ fcnt, const int* __restrict__ flist,
    int* __restrict__ idxbuf)
{
    __shared__ double h0s[HD];
    __shared__ double h1s[HD];
    __shared__ double ep[16][17];
    __shared__ double es[CD];
    __shared__ double dmin[256];
    __shared__ int    imin[256];

    int n = *fcnt;
    if (n > BATCH * OBS) n = BATCH * OBS;
    const int j = threadIdx.x;

    for (int f = blockIdx.x; f < n; f += gridDim.x) {
        const int T = flist[f];
        const int b = T >> 5, t = T & 31;
        const double x = (double)obs[b * OBS + t];
        {
            double a = fma(x, (double)W0[j], (double)W0[(1 + t) * HD + j])
                     + (double)B0[j];
            h0s[j] = a > 0.0 ? a : 0.0;
        }
        __syncthreads();
        {
            double s = 0.0;
            for (int k = 0; k < HD; ++k)
                s = fma(h0s[k], (double)W1[k * HD + j], s);
            s += (double)B1[j];
            h1s[j] = s > 0.0 ? s : 0.0;
        }
        __syncthreads();
        {
            const int d = j & 15, part = j >> 4;
            double s = 0.0;
            for (int k = part * 16; k < part * 16 + 16; ++k)
                s = fma(h1s[k], (double)W2[k * CD + d], s);
            ep[part][d] = s;
        }
        __syncthreads();
        if (j < CD) {
            double s = 0.0;
            for (int p = 0; p < 16; ++p) s += ep[p][j];
            es[j] = s + (double)B2[j];
        }
        __syncthreads();
        {
            double best = 1e300; int bi = 0x7fffffff;
            for (int c = j; c < NC; c += 256) {
                double dot = 0.0;
                #pragma unroll
                for (int q = 0; q < CD; ++q)
                    dot = fma(es[q], (double)cb[c * CD + q], dot);
                double D = n64[c] - 2.0 * dot;
                if (D < best || (D == best && c < bi)) { best = D; bi = c; }
            }
            dmin[j] = best; imin[j] = bi;
        }
        __syncthreads();
        if (j == 0) {
            double best = dmin[0]; int bi = imin[0];
            for (int k = 1; k < 256; ++k)
                if (dmin[k] < best || (dmin[k] == best && imin[k] < bi)) {
                    best = dmin[k]; bi = imin[k];
                }
            idxbuf[T] = bi;
        }
        __syncthreads();
    }
}

// ---------------------------------------------------------------------------
// Kernel 3: decoder MLP 512 -> 256 -> 256 -> 32, 16 batch rows per block.
// Gathers q rows from the codebook via idxbuf (q never materialized).
// ---------------------------------------------------------------------------
__global__ void __launch_bounds__(256) decoder_kernel(
    const int* __restrict__ idx, const float* __restrict__ cbk,
    const float* __restrict__ W0, const float* __restrict__ B0,
    const float* __restrict__ W1, const float* __restrict__ B1,
    const float* __restrict__ W2, const float* __restrict__ B2,
    float* __restrict__ out)
{
    __shared__ float qb[16][512];   // 32 KB: q, later reused as h2[16][256]
    __shared__ float hb[16][256];   // 16 KB
    const int tid = threadIdx.x;
    const int row0 = blockIdx.x * 16;

    {   // gather q rows: 2 tokens per thread from L1-resident codebook
        const int base = row0 * OBS;
        #pragma unroll
        for (int m = 0; m < 2; ++m) {
            int g = tid * 2 + m;
            int ciq = idx[base + g];
            const float4* src = (const float4*)(cbk + ciq * CD);
            float4* dst = (float4*)&qb[g >> 5][(g & 31) * CD];
            dst[0] = src[0]; dst[1] = src[1]; dst[2] = src[2]; dst[3] = src[3];
        }
    }
    __syncthreads();

    const int jg = tid & 63, tg = tid >> 6;
    const int j0 = jg * 4, r0 = tg * 4;

    // ---- layer 0: K=512 ----
    {
        float acA[4][4], acB[4][4];
        #pragma unroll
        for (int tt = 0; tt < 4; ++tt)
            #pragma unroll
            for (int u = 0; u < 4; ++u) { acA[tt][u] = 0.f; acB[tt][u] = 0.f; }
        for (int k = 0; k < 512; k += 4) {
            float hr[4][4];
            #pragma unroll
            for (int tt = 0; tt < 4; ++tt) {
                float4 hv = *(const float4*)&qb[r0 + tt][k];
                hr[tt][0] = hv.x; hr[tt][1] = hv.y; hr[tt][2] = hv.z; hr[tt][3] = hv.w;
            }
            #pragma unroll
            for (int p = 0; p < 4; ++p) {
                float4 w = *(const float4*)(W0 + (k + p) * 256 + j0);
                if (p < 2) {
                    #pragma unroll
                    for (int tt = 0; tt < 4; ++tt) {
                        acA[tt][0] = fmaf(hr[tt][p], w.x, acA[tt][0]);
                        acA[tt][1] = fmaf(hr[tt][p], w.y, acA[tt][1]);
                        acA[tt][2] = fmaf(hr[tt][p], w.z, acA[tt][2]);
                        acA[tt][3] = fmaf(hr[tt][p], w.w, acA[tt][3]);
                    }
                } else {
                    #pragma unroll
                    for (int tt = 0; tt < 4; ++tt) {
                        acB[tt][0] = fmaf(hr[tt][p], w.x, acB[tt][0]);
                        acB[tt][1] = fmaf(hr[tt][p], w.y, acB[tt][1]);
                        acB[tt][2] = fmaf(hr[tt][p], w.z, acB[tt][2]);
                        acB[tt][3] = fmaf(hr[tt][p], w.w, acB[tt][3]);
                    }
                }
            }
        }
        #pragma unroll
        for (int tt = 0; tt < 4; ++tt)
            #pragma unroll
            for (int u = 0; u < 4; ++u)
                hb[r0 + tt][j0 + u] = fmaxf((acA[tt][u] + acB[tt][u]) + B0[j0 + u], 0.f);
    }
    __syncthreads();

    // ---- layer 1: K=256, write h2 into qb storage ----
    float* h2 = &qb[0][0];
    {
        float acA[4][4], acB[4][4];
        #pragma unroll
        for (int tt = 0; tt < 4; ++tt)
            #pragma unroll
            for (int u = 0; u < 4; ++u) { acA[tt][u] = 0.f; acB[tt][u] = 0.f; }
        for (int k = 0; k < 256; k += 4) {
            float hr[4][4];
            #pragma unroll
            for (int tt = 0; tt < 4; ++tt) {
                float4 hv = *(const float4*)&hb[r0 + tt][k];
                hr[tt][0] = hv.x; hr[tt][1] = hv.y; hr[tt][2] = hv.z; hr[tt][3] = hv.w;
            }
            #pragma unroll
            for (int p = 0; p < 4; ++p) {
                float4 w = *(const float4*)(W1 + (k + p) * 256 + j0);
                if (p < 2) {
                    #pragma unroll
                    for (int tt = 0; tt < 4; ++tt) {
                        acA[tt][0] = fmaf(hr[tt][p], w.x, acA[tt][0]);
                        acA[tt][1] = fmaf(hr[tt][p], w.y, acA[tt][1]);
                        acA[tt][2] = fmaf(hr[tt][p], w.z, acA[tt][2]);
                        acA[tt][3] = fmaf(hr[tt][p], w.w, acA[tt][3]);
                    }
                } else {
                    #pragma unroll
                    for (int tt = 0; tt < 4; ++tt) {
                        acB[tt][0] = fmaf(hr[tt][p], w.x, acB[tt][0]);
                        acB[tt][1] = fmaf(hr[tt][p], w.y, acB[tt][1]);
                        acB[tt][2] = fmaf(hr[tt][p], w.z, acB[tt][2]);
                        acB[tt][3] = fmaf(hr[tt][p], w.w, acB[tt][3]);
                    }
                }
            }
        }
        __syncthreads();
        #pragma unroll
        for (int tt = 0; tt < 4; ++tt)
            #pragma unroll
            for (int u = 0; u < 4; ++u)
                h2[(r0 + tt) * 256 + j0 + u] =
                    fmaxf((acA[tt][u] + acB[tt][u]) + B1[j0 + u], 0.f);
    }
    __syncthreads();

    // ---- layer 2: N=32 output, no relu ----
    {
        const int c  = tid & 31;
        const int rg = tid >> 5;
        for (int rr = rg; rr < 16; rr += 8) {
            float a0 = 0.f, a1 = 0.f, a2 = 0.f, a3 = 0.f;
            #pragma unroll 4
            for (int k = 0; k < 256; k += 4) {
                float4 hv = *(const float4*)&h2[rr * 256 + k];
                a0 = fmaf(hv.x, W2[(k + 0) * 32 + c], a0);
                a1 = fmaf(hv.y, W2[(k + 1) * 32 + c], a1);
                a2 = fmaf(hv.z, W2[(k + 2) * 32 + c], a2);
                a3 = fmaf(hv.w, W2[(k + 3) * 32 + c], a3);
            }
            out[(row0 + rr) * 32 + c] = ((a0 + a1) + (a2 + a3)) + B2[c];
        }
    }
}

// ---------------------------------------------------------------------------
extern "C" void kernel_launch(void* const* d_in, const int* in_sizes, int n_in,
                              void* d_out, int out_size, void* d_ws, size_t ws_size,
                              hipStream_t stream) {
    (void)in_sizes; (void)n_in; (void)out_size; (void)ws_size;
    const float* obs = (const float*)d_in[0];
    const float* eW0 = (const float*)d_in[1];
    const float* eb0 = (const float*)d_in[2];
    const float* eW1 = (const float*)d_in[3];
    const float* eb1 = (const float*)d_in[4];
    const float* eW2 = (const float*)d_in[5];
    const float* eb2 = (const float*)d_in[6];
    const float* dW0 = (const float*)d_in[7];
    const float* db0 = (const float*)d_in[8];
    const float* dW1 = (const float*)d_in[9];
    const float* db1 = (const float*)d_in[10];
    const float* dW2 = (const float*)d_in[11];
    const float* db2 = (const float*)d_in[12];
    const float* cb  = (const float*)d_in[13];

    char*   ws    = (char*)d_ws;
    float*  n32   = (float*)ws;                          // 2 KB
    double* n64   = (double*)(ws + 4096);                // 4 KB
    int*    fcnt  = (int*)(ws + 8192);                   // 4 B
    int*    flist = (int*)(ws + 8448);                   // 1 MB (worst case)
    int*    idxb  = (int*)(ws + 8448 + 1048576);         // 1 MB

    cb_norms_kernel<<<2, 256, 0, stream>>>(cb, n32, n64, fcnt);
    encoder_kernel<<<BATCH, 256, 0, stream>>>(obs, eW0, eb0, eW1, eb1, eW2, eb2,
                                              cb, n32, idxb, fcnt, flist);
    fixup_kernel<<<256, 256, 0, stream>>>(obs, eW0, eb0, eW1, eb1, eW2, eb2,
                                          cb, n64, fcnt, flist, idxb);
    decoder_kernel<<<BATCH / 16, 256, 0, stream>>>(idxb, cb, dW0, db0, dW1, db1,
                                                   dW2, db2, (float*)d_out);
}